// Round 2
// baseline (78.630 us; speedup 1.0000x reference)
//
#include <hip/hip_runtime.h>
#include <math.h>

// Problem constants (fixed by setup_inputs)
constexpr int B       = 2;
constexpr int N       = 32768;
constexpr int D       = 3;
constexpr int M_FULL  = 8192;
constexpr int SUBDIV  = 8;
constexpr int M       = M_FULL / SUBDIV;   // 1024 subsampled verts per (b,d)
constexpr int K       = 512;               // value buckets over [-4,4]
constexpr float LO    = -4.0f;
constexpr float INV_W = 64.0f;             // 1 / (8/512)
constexpr float K4    = 5.770780163555852f; // 4*log2(e): e^{4t} = 2^{K4*t}

// Single fused kernel, whole grid co-resident:
// 768 blocks x 256 threads = 3 blocks/CU (12 waves/CU), LDS 22KB/block.
constexpr int BLOCK   = 256;
constexpr int CHUNKS  = N / BLOCK;         // 128
constexpr int GRID    = B * D * CHUNKS;    // 768
constexpr int VPT     = M / BLOCK;         // 4 verts per thread in the build

// ---- 512-element wave-parallel scans (one wave, lane owns 8 slots) ----
__device__ inline void scan512_pre(float* a) {   // exclusive prefix, small-first
    const int lane = threadIdx.x & 63;
    const int base = lane * 8;
    float xv[8], e[8]; float ls = 0.f;
    #pragma unroll
    for (int t = 0; t < 8; ++t) xv[t] = a[base + t];
    #pragma unroll
    for (int t = 0; t < 8; ++t) { e[t] = ls; ls += xv[t]; }
    float inc = ls;
    #pragma unroll
    for (int off = 1; off < 64; off <<= 1) {
        const float tmp = __shfl_up(inc, off, 64);
        if (lane >= off) inc += tmp;
    }
    const float exoff = inc - ls;
    #pragma unroll
    for (int t = 0; t < 8; ++t) a[base + t] = exoff + e[t];
}

__device__ inline void scan512_suf(float* a) {   // inclusive suffix, small-first
    const int lane = threadIdx.x & 63;
    const int base = lane * 8;
    float xv[8], e[8]; float ls = 0.f;
    #pragma unroll
    for (int t = 0; t < 8; ++t) xv[t] = a[base + t];
    #pragma unroll
    for (int t = 7; t >= 0; --t) { e[t] = ls; ls += xv[t]; }
    float inc = ls;
    #pragma unroll
    for (int off = 1; off < 64; off <<= 1) {
        const float tmp = __shfl_down(inc, off, 64);
        if (lane + off < 64) inc += tmp;
    }
    const float exoff = inc - ls;
    #pragma unroll
    for (int t = 0; t < 8; ++t) a[base + t] = exoff + e[t] + xv[t];
}

__device__ inline void scan512_i(const int* cntA, int* begA, int* curA) {
    const int lane = threadIdx.x & 63;
    const int base = lane * 8;
    int xv[8], e[8]; int ls = 0;
    #pragma unroll
    for (int t = 0; t < 8; ++t) xv[t] = cntA[base + t];
    #pragma unroll
    for (int t = 0; t < 8; ++t) { e[t] = ls; ls += xv[t]; }
    int inc = ls;
    #pragma unroll
    for (int off = 1; off < 64; off <<= 1) {
        const int tmp = __shfl_up(inc, off, 64);
        if (lane >= off) inc += tmp;
    }
    const int exoff = inc - ls;
    #pragma unroll
    for (int t = 0; t < 8; ++t) {
        begA[base + t] = exoff + e[t];
        curA[base + t] = exoff + e[t];
    }
}

__global__ __launch_bounds__(BLOCK) void deformer_fused(
    const float* __restrict__ x,
    const float* __restrict__ dverts,
    const float* __restrict__ mverts,
    float* __restrict__ out)
{
    __shared__ float2 vw[M];                       // 8 KB bucket-grouped (v,w)
    __shared__ float  gAp[K], gSp[K], gAm[K], gSm[K]; // 8 KB aggregates
    __shared__ int    cnt[K], beg[K], cur[K];         // 6 KB

    const int tid = threadIdx.x;
    const int p = blockIdx.x >> 7;    // pair 0..5
    const int c = blockIdx.x & 127;   // chunk within pair
    const int b = p / 3, d = p % 3;

    // Hoist the x load: its HBM latency hides under the whole build phase.
    const int n = c * BLOCK + tid;
    const int o = (b * N + n) * D + d;
    const float xq = x[o];

    // Zero aggregates (2 slots per thread).
    cnt[tid] = 0;       cnt[tid + 256] = 0;
    gAp[tid] = 0.f;     gAp[tid + 256] = 0.f;
    gSp[tid] = 0.f;     gSp[tid + 256] = 0.f;
    gAm[tid] = 0.f;     gAm[tid + 256] = 0.f;
    gSm[tid] = 0.f;     gSm[tid + 256] = 0.f;
    __syncthreads();

    // ---- Build: 4 verts per thread ----
    float vv[VPT], wv[VPT];
    #pragma unroll
    for (int r = 0; r < VPT; ++r) {
        const int m = tid + r * BLOCK;
        const int g = (b * M_FULL + m * SUBDIV) * D + d;
        vv[r] = dverts[g];
        wv[r] = mverts[g];
    }
    int bjv[VPT];
    #pragma unroll
    for (int r = 0; r < VPT; ++r) {
        const float v = vv[r], w = wv[r];
        const float epv = __builtin_amdgcn_exp2f( K4 * v);  // e^{4v}
        const float emv = __builtin_amdgcn_exp2f(-K4 * v);  // e^{-4v}
        int bj = (int)floorf((v - LO) * INV_W);
        bj = bj < 0 ? 0 : (bj > K - 1 ? K - 1 : bj);
        bjv[r] = bj;
        atomicAdd(&cnt[bj], 1);
        atomicAdd(&gAp[bj], w * epv);
        atomicAdd(&gSp[bj], epv);
        atomicAdd(&gAm[bj], w * emv);
        atomicAdd(&gSm[bj], emv);
    }
    __syncthreads();

    // Scans on 4 waves (wave 0 takes the cheap int scan plus one suffix scan).
    const int wid = tid >> 6;
    if      (wid == 0) { scan512_i(cnt, beg, cur); scan512_suf(gSm); }
    else if (wid == 1) scan512_pre(gAp);   // exclusive prefix (buckets < j)
    else if (wid == 2) scan512_pre(gSp);
    else if (wid == 3) scan512_suf(gAm);   // inclusive suffix (buckets >= j)
    __syncthreads();

    // Counting scatter of (v,w) into bucket-grouped order.
    #pragma unroll
    for (int r = 0; r < VPT; ++r) {
        const int pos = atomicAdd(&cur[bjv[r]], 1);
        vw[pos] = make_float2(vv[r], wv[r]);
    }
    __syncthreads();

    // ---- Query: one output element per thread ----
    int j = (int)floorf((xq - LO) * INV_W);
    j = j < 0 ? 0 : (j > K - 1 ? K - 1 : j);

    const float en  = __builtin_amdgcn_exp2f(-K4 * xq);  // e^{-4x}
    const float epx = __builtin_amdgcn_exp2f( K4 * xq);  // e^{+4x}

    const float Ap = gAp[j], Sp = gSp[j];                // buckets strictly below j
    const float Am = (j < K - 1) ? gAm[j + 1] : 0.f;     // buckets strictly above j
    const float Sm = (j < K - 1) ? gSm[j + 1] : 0.f;

    // After the scatter, cur[j] == beg[j] + cnt[j]: reuse it as the end fence.
    const int s0 = beg[j], s1 = cur[j];
    float rN = 0.f, rD = 0.f;
    for (int i = s0; i < s1; ++i) {
        const float2 pv = vw[i];                         // one ds_read_b64
        const float e2 = __builtin_amdgcn_exp2f(-K4 * fabsf(xq - pv.x));
        rN += pv.y * e2;
        rD += e2;
    }
    out[o] = (en * Ap + epx * Am + rN) / (en * Sp + epx * Sm + rD);
}

extern "C" void kernel_launch(void* const* d_in, const int* in_sizes, int n_in,
                              void* d_out, int out_size, void* d_ws, size_t ws_size,
                              hipStream_t stream) {
    const float* x  = (const float*)d_in[0];
    const float* dv = (const float*)d_in[1];
    const float* mv = (const float*)d_in[2];
    float* out = (float*)d_out;

    deformer_fused<<<GRID, BLOCK, 0, stream>>>(x, dv, mv, out);
}

// Round 3
// 63.979 us; speedup vs baseline: 1.2290x; 1.2290x over previous
//
#include <hip/hip_runtime.h>
#include <math.h>

// Problem constants (fixed by setup_inputs)
constexpr int B       = 2;
constexpr int N       = 32768;
constexpr int D       = 3;
constexpr int M_FULL  = 8192;
constexpr int SUBDIV  = 8;
constexpr int M       = M_FULL / SUBDIV;   // 1024 subsampled verts per (b,d)
constexpr int K       = 512;               // value buckets over [-4,4]
constexpr float LO    = -4.0f;
constexpr float INV_W = 64.0f;             // 1 / (8/512)
constexpr float K4    = 5.770780163555852f; // 4*log2(e): e^{4t} = 2^{K4*t}

// Round-0 geometry (lowest builds/CU for a single launch): 192 blocks x 1024
// threads, 1 block/CU, 16 waves. Build cost cut from 6 LDS atomics/vert to 2.
constexpr int BLOCK   = 1024;
constexpr int CHUNKS  = N / BLOCK;         // 32
constexpr int GRID    = B * D * CHUNKS;    // 192

// ---- 512-element wave-parallel scans (one wave, lane owns 8 slots) ----
__device__ inline void scan512_pre(float* a) {   // exclusive prefix, small-first
    const int lane = threadIdx.x & 63;
    const int base = lane * 8;
    float xv[8], e[8]; float ls = 0.f;
    #pragma unroll
    for (int t = 0; t < 8; ++t) xv[t] = a[base + t];
    #pragma unroll
    for (int t = 0; t < 8; ++t) { e[t] = ls; ls += xv[t]; }
    float inc = ls;
    #pragma unroll
    for (int off = 1; off < 64; off <<= 1) {
        const float tmp = __shfl_up(inc, off, 64);
        if (lane >= off) inc += tmp;
    }
    const float exoff = inc - ls;
    #pragma unroll
    for (int t = 0; t < 8; ++t) a[base + t] = exoff + e[t];
}

__device__ inline void scan512_suf(float* a) {   // inclusive suffix, small-first
    const int lane = threadIdx.x & 63;
    const int base = lane * 8;
    float xv[8], e[8]; float ls = 0.f;
    #pragma unroll
    for (int t = 0; t < 8; ++t) xv[t] = a[base + t];
    #pragma unroll
    for (int t = 7; t >= 0; --t) { e[t] = ls; ls += xv[t]; }
    float inc = ls;
    #pragma unroll
    for (int off = 1; off < 64; off <<= 1) {
        const float tmp = __shfl_down(inc, off, 64);
        if (lane + off < 64) inc += tmp;
    }
    const float exoff = inc - ls;
    #pragma unroll
    for (int t = 0; t < 8; ++t) a[base + t] = exoff + e[t] + xv[t];
}

__device__ inline void scan512_i(const int* cntA, int* begA, int* curA) {
    const int lane = threadIdx.x & 63;
    const int base = lane * 8;
    int xv[8], e[8]; int ls = 0;
    #pragma unroll
    for (int t = 0; t < 8; ++t) xv[t] = cntA[base + t];
    #pragma unroll
    for (int t = 0; t < 8; ++t) { e[t] = ls; ls += xv[t]; }
    int inc = ls;
    #pragma unroll
    for (int off = 1; off < 64; off <<= 1) {
        const int tmp = __shfl_up(inc, off, 64);
        if (lane >= off) inc += tmp;
    }
    const int exoff = inc - ls;
    #pragma unroll
    for (int t = 0; t < 8; ++t) {
        begA[base + t] = exoff + e[t];
        curA[base + t] = exoff + e[t];
    }
}

__global__ __launch_bounds__(BLOCK) void deformer_fused(
    const float* __restrict__ x,
    const float* __restrict__ dverts,
    const float* __restrict__ mverts,
    float* __restrict__ out)
{
    __shared__ float2 vw[M];                          // 8 KB bucket-grouped (v,w)
    __shared__ float  gAp[K], gSp[K], gAm[K], gSm[K]; // 8 KB aggregates
    __shared__ int    cnt[K], beg[K], cur[K];         // 6 KB

    const int tid = threadIdx.x;
    const int p = blockIdx.x >> 5;    // pair 0..5
    const int c = blockIdx.x & 31;    // chunk within pair
    const int b = p / 3, d = p % 3;

    // Hoist both global loads: HBM/L2 latency hides under zeroing + histogram.
    const int n = c * BLOCK + tid;
    const int o = (b * N + n) * D + d;
    const float xq = x[o];

    const int g = (b * M_FULL + tid * SUBDIV) * D + d;
    const float v = dverts[g];
    const float w = mverts[g];

    if (tid < K) cnt[tid] = 0;
    __syncthreads();

    // ---- Histogram: ONE int atomic per vert (was 5 incl. 4 float adds) ----
    int bj = (int)floorf((v - LO) * INV_W);
    bj = bj < 0 ? 0 : (bj > K - 1 ? K - 1 : bj);
    atomicAdd(&cnt[bj], 1);
    __syncthreads();

    if (tid < 64) scan512_i(cnt, beg, cur);   // wave 0; others idle briefly
    __syncthreads();

    // ---- Counting scatter: second (and last) atomic per vert ----
    const int pos = atomicAdd(&cur[bj], 1);
    vw[pos] = make_float2(v, w);
    __syncthreads();

    // ---- Per-bucket segmented sums (replaces the float atomics) ----
    // vw is now bucket-grouped; thread j owns bucket j's segment (avg 2 elems).
    if (tid < K) {
        const int s0 = beg[tid], s1 = cur[tid];   // cur == beg + cnt
        float ap = 0.f, sp = 0.f, am = 0.f, sm = 0.f;
        for (int i = s0; i < s1; ++i) {
            const float2 pv = vw[i];
            const float epv = __builtin_amdgcn_exp2f( K4 * pv.x);  // e^{4v}
            const float emv = __builtin_amdgcn_exp2f(-K4 * pv.x);  // e^{-4v}
            ap += pv.y * epv; sp += epv;
            am += pv.y * emv; sm += emv;
        }
        gAp[tid] = ap; gSp[tid] = sp; gAm[tid] = am; gSm[tid] = sm;
    }
    __syncthreads();

    // Scans: 4 scans on 4 separate waves, concurrent.
    const int wid = tid >> 6;
    if      (wid == 0) scan512_pre(gAp);   // exclusive prefix (buckets < j)
    else if (wid == 1) scan512_pre(gSp);
    else if (wid == 2) scan512_suf(gAm);   // inclusive suffix (buckets >= j)
    else if (wid == 3) scan512_suf(gSm);
    __syncthreads();

    // ---- Query: one output element per thread ----
    int j = (int)floorf((xq - LO) * INV_W);
    j = j < 0 ? 0 : (j > K - 1 ? K - 1 : j);

    const float en  = __builtin_amdgcn_exp2f(-K4 * xq);  // e^{-4x}
    const float epx = __builtin_amdgcn_exp2f( K4 * xq);  // e^{+4x}

    const float Ap = gAp[j], Sp = gSp[j];                // buckets strictly below j
    const float Am = (j < K - 1) ? gAm[j + 1] : 0.f;     // buckets strictly above j
    const float Sm = (j < K - 1) ? gSm[j + 1] : 0.f;

    const int s0 = beg[j], s1 = cur[j];                  // cur == end fence
    float rN = 0.f, rD = 0.f;
    for (int i = s0; i < s1; ++i) {
        const float2 pv = vw[i];                         // one ds_read_b64
        const float e2 = __builtin_amdgcn_exp2f(-K4 * fabsf(xq - pv.x));
        rN += pv.y * e2;
        rD += e2;
    }
    out[o] = (en * Ap + epx * Am + rN) / (en * Sp + epx * Sm + rD);
}

extern "C" void kernel_launch(void* const* d_in, const int* in_sizes, int n_in,
                              void* d_out, int out_size, void* d_ws, size_t ws_size,
                              hipStream_t stream) {
    const float* x  = (const float*)d_in[0];
    const float* dv = (const float*)d_in[1];
    const float* mv = (const float*)d_in[2];
    float* out = (float*)d_out;

    deformer_fused<<<GRID, BLOCK, 0, stream>>>(x, dv, mv, out);
}

// Round 6
// 63.965 us; speedup vs baseline: 1.2293x; 1.0002x over previous
//
#include <hip/hip_runtime.h>
#include <math.h>

// Problem constants (fixed by setup_inputs)
constexpr int B       = 2;
constexpr int N       = 32768;
constexpr int D       = 3;
constexpr int M_FULL  = 8192;
constexpr int SUBDIV  = 8;
constexpr int M       = M_FULL / SUBDIV;   // 1024 subsampled verts per (b,d)
constexpr int K       = 512;               // value buckets over [-4,4]
constexpr float LO    = -4.0f;
constexpr float INV_W = 64.0f;             // 1 / (8/512)
constexpr float K4    = 5.770780163555852f; // 4*log2(e): e^{4t} = 2^{K4*t}

// 192 blocks x 1024 threads: 1 block/CU, lowest builds/CU for a single launch.
// Build cost: ONE LDS atomic per vert (histogram; its return value is the
// scatter rank), scatter is atomic-free.
constexpr int BLOCK   = 1024;
constexpr int CHUNKS  = N / BLOCK;         // 32
constexpr int GRID    = B * D * CHUNKS;    // 192

// ---- 512-element wave-parallel scans (one wave, lane owns 8 slots) ----
__device__ inline void scan512_pre(float* a) {   // exclusive prefix, small-first
    const int lane = threadIdx.x & 63;
    const int base = lane * 8;
    float xv[8], e[8]; float ls = 0.f;
    #pragma unroll
    for (int t = 0; t < 8; ++t) xv[t] = a[base + t];
    #pragma unroll
    for (int t = 0; t < 8; ++t) { e[t] = ls; ls += xv[t]; }
    float inc = ls;
    #pragma unroll
    for (int off = 1; off < 64; off <<= 1) {
        const float tmp = __shfl_up(inc, off, 64);
        if (lane >= off) inc += tmp;
    }
    const float exoff = inc - ls;
    #pragma unroll
    for (int t = 0; t < 8; ++t) a[base + t] = exoff + e[t];
}

__device__ inline void scan512_suf(float* a) {   // inclusive suffix, small-first
    const int lane = threadIdx.x & 63;
    const int base = lane * 8;
    float xv[8], e[8]; float ls = 0.f;
    #pragma unroll
    for (int t = 0; t < 8; ++t) xv[t] = a[base + t];
    #pragma unroll
    for (int t = 7; t >= 0; --t) { e[t] = ls; ls += xv[t]; }
    float inc = ls;
    #pragma unroll
    for (int off = 1; off < 64; off <<= 1) {
        const float tmp = __shfl_down(inc, off, 64);
        if (lane + off < 64) inc += tmp;
    }
    const float exoff = inc - ls;
    #pragma unroll
    for (int t = 0; t < 8; ++t) a[base + t] = exoff + e[t] + xv[t];
}

__device__ inline void scan512_i(const int* cntA, int* begA) {  // exclusive prefix
    const int lane = threadIdx.x & 63;
    const int base = lane * 8;
    int xv[8], e[8]; int ls = 0;
    #pragma unroll
    for (int t = 0; t < 8; ++t) xv[t] = cntA[base + t];
    #pragma unroll
    for (int t = 0; t < 8; ++t) { e[t] = ls; ls += xv[t]; }
    int inc = ls;
    #pragma unroll
    for (int off = 1; off < 64; off <<= 1) {
        const int tmp = __shfl_up(inc, off, 64);
        if (lane >= off) inc += tmp;
    }
    const int exoff = inc - ls;
    #pragma unroll
    for (int t = 0; t < 8; ++t) begA[base + t] = exoff + e[t];
}

__global__ __launch_bounds__(BLOCK) void deformer_fused(
    const float* __restrict__ x,
    const float* __restrict__ dverts,
    const float* __restrict__ mverts,
    float* __restrict__ out)
{
    __shared__ float2 vw[M];                          // 8 KB bucket-grouped (v,w)
    __shared__ float  gAp[K], gSp[K], gAm[K], gSm[K]; // 8 KB aggregates
    __shared__ int    cnt[K], beg[K];                 // 4 KB

    const int tid = threadIdx.x;
    const int p = blockIdx.x >> 5;    // pair 0..5
    const int c = blockIdx.x & 31;    // chunk within pair
    const int b = p / 3, d = p % 3;

    // Hoist all global loads: HBM/L2 latency hides under zeroing + histogram.
    const int n = c * BLOCK + tid;
    const int o = (b * N + n) * D + d;
    const float xq = x[o];

    const int g = (b * M_FULL + tid * SUBDIV) * D + d;
    const float v = dverts[g];
    const float w = mverts[g];

    if (tid < K) cnt[tid] = 0;
    __syncthreads();

    // ---- Histogram: the ONLY atomic. Old value = this vert's bucket rank. ----
    int bj = (int)floorf((v - LO) * INV_W);
    bj = bj < 0 ? 0 : (bj > K - 1 ? K - 1 : bj);
    const int rank = atomicAdd(&cnt[bj], 1);
    __syncthreads();

    if (tid < 64) scan512_i(cnt, beg);   // wave 0; exclusive prefix of counts
    __syncthreads();

    // ---- Atomic-free scatter: destination = bucket base + histogram rank ----
    vw[beg[bj] + rank] = make_float2(v, w);
    __syncthreads();

    // ---- Per-bucket segmented sums (thread j owns bucket j, avg 2 elems) ----
    if (tid < K) {
        const int s0 = beg[tid], s1 = s0 + cnt[tid];
        float ap = 0.f, sp = 0.f, am = 0.f, sm = 0.f;
        for (int i = s0; i < s1; ++i) {
            const float2 pv = vw[i];
            const float epv = __builtin_amdgcn_exp2f( K4 * pv.x);  // e^{4v}
            const float emv = __builtin_amdgcn_exp2f(-K4 * pv.x);  // e^{-4v}
            ap += pv.y * epv; sp += epv;
            am += pv.y * emv; sm += emv;
        }
        gAp[tid] = ap; gSp[tid] = sp; gAm[tid] = am; gSm[tid] = sm;
    }
    __syncthreads();

    // Scans: 4 scans on 4 separate waves, concurrent.
    const int wid = tid >> 6;
    if      (wid == 0) scan512_pre(gAp);   // exclusive prefix (buckets < j)
    else if (wid == 1) scan512_pre(gSp);
    else if (wid == 2) scan512_suf(gAm);   // inclusive suffix (buckets >= j)
    else if (wid == 3) scan512_suf(gSm);
    __syncthreads();

    // ---- Query: one output element per thread ----
    int j = (int)floorf((xq - LO) * INV_W);
    j = j < 0 ? 0 : (j > K - 1 ? K - 1 : j);

    const float en  = __builtin_amdgcn_exp2f(-K4 * xq);  // e^{-4x}
    const float epx = __builtin_amdgcn_exp2f( K4 * xq);  // e^{+4x}

    const float Ap = gAp[j], Sp = gSp[j];                // buckets strictly below j
    const float Am = (j < K - 1) ? gAm[j + 1] : 0.f;     // buckets strictly above j
    const float Sm = (j < K - 1) ? gSm[j + 1] : 0.f;

    const int s0 = beg[j], s1 = s0 + cnt[j];
    float rN = 0.f, rD = 0.f;
    for (int i = s0; i < s1; ++i) {
        const float2 pv = vw[i];                         // one ds_read_b64
        const float e2 = __builtin_amdgcn_exp2f(-K4 * fabsf(xq - pv.x));
        rN += pv.y * e2;
        rD += e2;
    }
    out[o] = (en * Ap + epx * Am + rN) / (en * Sp + epx * Sm + rD);
}

extern "C" void kernel_launch(void* const* d_in, const int* in_sizes, int n_in,
                              void* d_out, int out_size, void* d_ws, size_t ws_size,
                              hipStream_t stream) {
    const float* x  = (const float*)d_in[0];
    const float* dv = (const float*)d_in[1];
    const float* mv = (const float*)d_in[2];
    float* out = (float*)d_out;

    deformer_fused<<<GRID, BLOCK, 0, stream>>>(x, dv, mv, out);
}